// Round 2
// baseline (616.762 us; speedup 1.0000x reference)
//
#include <hip/hip_runtime.h>
#include <stdint.h>

typedef __attribute__((ext_vector_type(4))) float f32x4;
typedef __attribute__((ext_vector_type(8))) short s16x8;

#define D_ 1024
#define LQ 2048
#define HH_ 8
#define HD_ 128

static __device__ __forceinline__ float bf2f(ushort u){
  union { unsigned int i; float f; } v; v.i = ((unsigned int)u) << 16; return v.f;
}
static __device__ __forceinline__ ushort f2bf(float f){
  union { float f; unsigned int i; } v; v.f = f;
  unsigned int r = v.i + 0x7fffu + ((v.i >> 16) & 1u);
  return (ushort)(r >> 16);
}

// ---------------- weight fp32 -> bf16 conversion (7 matrices of 1M) --------
struct WP { const float* s[7]; };
__global__ __launch_bounds__(256) void convert_weights(WP wp, ushort* __restrict__ dst){
  int w = blockIdx.x >> 7, blk = blockIdx.x & 127, t = threadIdx.x;
  const float4* s = (const float4*)wp.s[w];
  ushort4* d = (ushort4*)(dst + (size_t)w * 1048576);
  int base = blk * 2048 + t;
  #pragma unroll
  for (int r = 0; r < 8; r++){
    float4 v = s[base + r * 256];
    ushort4 o; o.x = f2bf(v.x); o.y = f2bf(v.y); o.z = f2bf(v.z); o.w = f2bf(v.w);
    d[base + r * 256] = o;
  }
}

// ---------------- layernorm: fp32 in -> bf16 (or fp32) out ------------------
template<int OUTF>
__global__ __launch_bounds__(256) void ln_kernel(const float* __restrict__ x,
    const float* __restrict__ g, const float* __restrict__ bb,
    float* __restrict__ outf, ushort* __restrict__ outb){
  int row = blockIdx.x, t = threadIdx.x;
  const float4* xr = (const float4*)(x + (size_t)row * D_);
  float4 v = xr[t];
  float s = v.x + v.y + v.z + v.w;
  float sq = v.x*v.x + v.y*v.y + v.z*v.z + v.w*v.w;
  #pragma unroll
  for (int o = 32; o; o >>= 1){ s += __shfl_down(s, o, 64); sq += __shfl_down(sq, o, 64); }
  __shared__ float red[8];
  int lane = t & 63, wv = t >> 6;
  if (!lane){ red[wv] = s; red[wv + 4] = sq; }
  __syncthreads();
  float S = red[0] + red[1] + red[2] + red[3];
  float SQ = red[4] + red[5] + red[6] + red[7];
  float m = S * (1.f / 1024.f);
  float var = SQ * (1.f / 1024.f) - m * m;
  float inv = rsqrtf(var + 1e-8f);
  float4 gv = ((const float4*)g)[t], bv = ((const float4*)bb)[t];
  float4 y;
  y.x = (v.x - m) * inv * gv.x + bv.x;
  y.y = (v.y - m) * inv * gv.y + bv.y;
  y.z = (v.z - m) * inv * gv.z + bv.z;
  y.w = (v.w - m) * inv * gv.w + bv.w;
  if (OUTF){
    ((float4*)outf)[(size_t)row * 256 + t] = y;
  } else {
    ushort4 o4; o4.x = f2bf(y.x); o4.y = f2bf(y.y); o4.z = f2bf(y.z); o4.w = f2bf(y.w);
    ((ushort4*)outb)[(size_t)row * 256 + t] = o4;
  }
}

// ---------------- GEMM: out[m,n] = sum_k A[m,k]*W[n,k] (+epilogue) ----------
// EPI: 0 = bias -> bf16 ; 1 = bias + residual -> fp32 ; 2 = bias + p*silu(p) -> bf16
//      3 = QKUV fused (N=4096, select dst/bias by n0>>10) -> bf16
struct P4 { ushort* d[4]; const float* b[4]; };

template<int EPI, int NB>
__global__ __launch_bounds__(256, 2) void gemm_k(
    const ushort* __restrict__ A, const ushort* __restrict__ W,
    P4 io, const float* __restrict__ resid, float* __restrict__ outf){
  __shared__ ushort As[128 * 32];
  __shared__ ushort Bs[128 * 32];
  int m0 = (blockIdx.x / NB) << 7;
  int n0 = (blockIdx.x % NB) << 7;
  int t = threadIdx.x, lane = t & 63, wv = t >> 6;
  int l15 = lane & 15, q8 = (lane >> 4) * 8;
  int wm = (wv & 1) << 6, wn = (wv >> 1) << 6;
  f32x4 acc[4][4] = {};
  for (int k0 = 0; k0 < 1024; k0 += 32){
    #pragma unroll
    for (int r = 0; r < 2; r++){
      int cb = r * 256 + wv * 64;   // wave-uniform chunk base
      int c = cb + lane;
      int row = c >> 2, kk = (c & 3) << 3;
      const ushort* ga = A + (size_t)(m0 + row) * 1024 + k0 + kk;
      const ushort* gb = W + (size_t)(n0 + row) * 1024 + k0 + kk;
      __builtin_amdgcn_global_load_lds(
          (const __attribute__((address_space(1))) unsigned int*)ga,
          (__attribute__((address_space(3))) unsigned int*)&As[cb * 8], 16, 0, 0);
      __builtin_amdgcn_global_load_lds(
          (const __attribute__((address_space(1))) unsigned int*)gb,
          (__attribute__((address_space(3))) unsigned int*)&Bs[cb * 8], 16, 0, 0);
    }
    __syncthreads();
    s16x8 afr[4], bfr[4];
    #pragma unroll
    for (int mi = 0; mi < 4; mi++) afr[mi] = *(const s16x8*)&As[(wm + mi * 16 + l15) * 32 + q8];
    #pragma unroll
    for (int ni = 0; ni < 4; ni++) bfr[ni] = *(const s16x8*)&Bs[(wn + ni * 16 + l15) * 32 + q8];
    #pragma unroll
    for (int mi = 0; mi < 4; mi++)
      #pragma unroll
      for (int ni = 0; ni < 4; ni++)
        acc[mi][ni] = __builtin_amdgcn_mfma_f32_16x16x32_bf16(afr[mi], bfr[ni], acc[mi][ni], 0, 0, 0);
    __syncthreads();
  }
  int sel = (EPI == 3) ? (n0 >> 10) : 0;
  ushort* dst = io.d[sel];
  const float* bias = io.b[sel];
  int ncol = (EPI == 3) ? (n0 & 1023) : n0;
  int quad = lane >> 4;
  #pragma unroll
  for (int mi = 0; mi < 4; mi++){
    int gm = m0 + wm + mi * 16 + quad * 4;
    #pragma unroll
    for (int ni = 0; ni < 4; ni++){
      int cn = ncol + wn + ni * 16 + l15;
      float bv = bias[cn];
      #pragma unroll
      for (int r = 0; r < 4; r++){
        float val = acc[mi][ni][r] + bv;
        size_t o = (size_t)(gm + r) * 1024 + cn;
        if (EPI == 1){ outf[o] = resid[o] + val; }
        else if (EPI == 2){ float sg = 1.f / (1.f + __expf(-val)); dst[o] = f2bf(val * val * sg); }
        else { dst[o] = f2bf(val); }
      }
    }
  }
}

// ---------------- RoPE in-place on Q and K (bf16, layout B,L,H*HD) ----------
__global__ __launch_bounds__(256) void rope_kernel(ushort* __restrict__ Q, ushort* __restrict__ K){
  int t0 = blockIdx.x * 256 + threadIdx.x;
  #pragma unroll
  for (int r = 0; r < 4; r++){
    int p = t0 + r * 524288;            // pair index; elements 2p,2p+1 = one dword
    int i = p & 63;                     // pair index within head (freq index 2i/128)
    int l = (p >> 9) & 2047;            // sequence position
    float freq = __expf(-(float)(2 * i) * 0.0078125f * 9.210340371976184f); // 10000^(-2i/128)
    float ang = (float)l * freq;
    float sv, cv; sincosf(ang, &sv, &cv);
    unsigned int* qp = (unsigned int*)Q + p;
    unsigned int u = *qp;
    float x1 = bf2f((ushort)(u & 0xffff)), x2 = bf2f((ushort)(u >> 16));
    *qp = (unsigned int)f2bf(x1 * cv - x2 * sv) | ((unsigned int)f2bf(x1 * sv + x2 * cv) << 16);
    unsigned int* kp = (unsigned int*)K + p;
    u = *kp;
    x1 = bf2f((ushort)(u & 0xffff)); x2 = bf2f((ushort)(u >> 16));
    *kp = (unsigned int)f2bf(x1 * cv - x2 * sv) | ((unsigned int)f2bf(x1 * sv + x2 * cv) << 16);
  }
}

// ---------------- V (B,L,H,HD) -> Vt (B,H,HD,L) -----------------------------
__global__ __launch_bounds__(256) void transpose_v(const ushort* __restrict__ Vb, ushort* __restrict__ Vt){
  int bidx = blockIdx.x;                 // 16 bh * 32 lt * 2 dt
  int dt = bidx & 1, lt = (bidx >> 1) & 31, bh = bidx >> 6;
  int b = bh >> 3, hh = bh & 7;
  int l0 = lt << 6, d0 = dt << 6;
  __shared__ ushort tile[64][66];
  int t = threadIdx.x;
  #pragma unroll
  for (int r = 0; r < 8; r++){
    int idx = r * 256 + t;
    int row = idx >> 5, cu = idx & 31;
    unsigned int val = *(const unsigned int*)(Vb + (size_t)(b * LQ + l0 + row) * D_ + hh * HD_ + d0 + cu * 2);
    *(unsigned int*)&tile[row][cu * 2] = val;
  }
  __syncthreads();
  #pragma unroll
  for (int r = 0; r < 8; r++){
    int idx = r * 256 + t;
    int drow = idx >> 5, lu = idx & 31;
    unsigned int val = (unsigned int)tile[lu * 2][drow] | ((unsigned int)tile[lu * 2 + 1][drow] << 16);
    *(unsigned int*)(Vt + ((size_t)(bh * HD_ + d0 + drow)) * LQ + l0 + lu * 2) = val;
  }
}

// ---------------- causal silu-attention, gated by U -------------------------
// out[b,q,h,d] = U * sum_{k<=q} silu(QK^T/sqrt(HD)) * V
__global__ __launch_bounds__(256, 2) void attn_kernel(
    const ushort* __restrict__ Q, const ushort* __restrict__ K,
    const ushort* __restrict__ Vt, const ushort* __restrict__ U,
    ushort* __restrict__ Aout){
  __shared__ ushort Qs[64 * 136];
  __shared__ ushort Ks[64 * 136];
  __shared__ ushort Vs[128 * 72];
  __shared__ ushort Ps[64 * 72];
  int t = threadIdx.x, lane = t & 63, wv = t >> 6;
  int l15 = lane & 15, quad = lane >> 4, q8 = quad * 8;
  int bh = blockIdx.x >> 4;
  int pairidx = blockIdx.x & 15;
  int b = bh >> 3, hh = bh & 7;
  const float scale = 0.08838834764831845f;  // 1/sqrt(128)
  for (int pass = 0; pass < 2; pass++){
    int qt = pass ? (31 - pairidx) : pairidx;   // balanced: (qt+1)+(32-qt)=33 iters/block
    int q0 = qt << 6;
    __syncthreads();
    #pragma unroll
    for (int r = 0; r < 4; r++){
      int c = r * 256 + t, row = c >> 4, ck = c & 15;
      *(s16x8*)&Qs[row * 136 + ck * 8] =
          *(const s16x8*)(Q + (size_t)(b * LQ + q0 + row) * D_ + hh * HD_ + ck * 8);
    }
    f32x4 acc_o[8] = {};
    int nkt = qt + 1;
    for (int kt = 0; kt < nkt; kt++){
      int k0 = kt << 6;
      __syncthreads();
      #pragma unroll
      for (int r = 0; r < 4; r++){
        int c = r * 256 + t, row = c >> 4, ck = c & 15;
        *(s16x8*)&Ks[row * 136 + ck * 8] =
            *(const s16x8*)(K + (size_t)(b * LQ + k0 + row) * D_ + hh * HD_ + ck * 8);
      }
      #pragma unroll
      for (int r = 0; r < 4; r++){
        int c = r * 256 + t, row = c >> 3, ck = c & 7;
        *(s16x8*)&Vs[row * 72 + ck * 8] =
            *(const s16x8*)(Vt + (size_t)(bh * HD_ + row) * LQ + k0 + ck * 8);
      }
      __syncthreads();
      f32x4 sacc[4] = {};
      int qrow = (wv << 4) + l15;
      #pragma unroll
      for (int kd = 0; kd < 4; kd++){
        s16x8 af = *(const s16x8*)&Qs[qrow * 136 + kd * 32 + q8];
        #pragma unroll
        for (int ni = 0; ni < 4; ni++){
          s16x8 bf = *(const s16x8*)&Ks[(ni * 16 + l15) * 136 + kd * 32 + q8];
          sacc[ni] = __builtin_amdgcn_mfma_f32_16x16x32_bf16(af, bf, sacc[ni], 0, 0, 0);
        }
      }
      int qg0 = q0 + (wv << 4) + quad * 4;
      #pragma unroll
      for (int ni = 0; ni < 4; ni++){
        int kg = k0 + ni * 16 + l15;
        #pragma unroll
        for (int r = 0; r < 4; r++){
          float s = sacc[ni][r] * scale;
          float p = (kg <= qg0 + r) ? (s / (1.f + __expf(-s))) : 0.f;
          Ps[((wv << 4) + quad * 4 + r) * 72 + ni * 16 + l15] = f2bf(p);
        }
      }
      __syncthreads();
      int prow = (wv << 4) + l15;
      #pragma unroll
      for (int kv = 0; kv < 2; kv++){
        s16x8 af = *(const s16x8*)&Ps[prow * 72 + kv * 32 + q8];
        #pragma unroll
        for (int nt = 0; nt < 8; nt++){
          s16x8 bf = *(const s16x8*)&Vs[(nt * 16 + l15) * 72 + kv * 32 + q8];
          acc_o[nt] = __builtin_amdgcn_mfma_f32_16x16x32_bf16(af, bf, acc_o[nt], 0, 0, 0);
        }
      }
    }
    #pragma unroll
    for (int nt = 0; nt < 8; nt++){
      #pragma unroll
      for (int r = 0; r < 4; r++){
        int qg = q0 + (wv << 4) + quad * 4 + r;
        int dd = nt * 16 + l15;
        size_t idx = (size_t)(b * LQ + qg) * D_ + hh * HD_ + dd;
        Aout[idx] = f2bf(acc_o[nt][r] * bf2f(U[idx]));
      }
    }
  }
}

// ---------------- launcher --------------------------------------------------
extern "C" void kernel_launch(void* const* d_in, const int* in_sizes, int n_in,
                              void* d_out, int out_size, void* d_ws, size_t ws_size,
                              hipStream_t stream){
  const float* seqs = (const float*)d_in[0];
  const float* bq = (const float*)d_in[3];
  const float* bk = (const float*)d_in[5];
  const float* bu = (const float*)d_in[7];
  const float* bv = (const float*)d_in[9];
  const float* bo = (const float*)d_in[11];
  const float* b1 = (const float*)d_in[13];
  const float* b2 = (const float*)d_in[15];
  const float* ln1g = (const float*)d_in[16];
  const float* ln1b = (const float*)d_in[17];
  const float* ln2g = (const float*)d_in[18];
  const float* ln2b = (const float*)d_in[19];
  const float* lnfg = (const float*)d_in[20];
  const float* lnfb = (const float*)d_in[21];

  char* base = (char*)d_ws;
  const size_t MB = 1u << 20;
  // Workspace map (78 MB total):
  //   wbf: 7 x 2 MB = 14 MB   (current layer's weights, bf16; reused per layer)
  //   h:   8 MB  (ln out, bf16; reused as attention output 'ab' after QKUV)
  //   Qb/Kb/Ub/Vb: 8 MB each
  //   Vt:  8 MB
  //   xb:  16 MB (fp32 residual stream)
  if (ws_size < 78 * MB) return;  // defensive: avoid OOB scribble if ws is small
  ushort* wbf = (ushort*)base;                   // 14 MB
  ushort* h   = (ushort*)(base + 14 * MB);       // 8 MB
  ushort* Qb  = (ushort*)(base + 22 * MB);       // 8 MB (also reused as MLP hidden)
  ushort* Kb  = (ushort*)(base + 30 * MB);       // 8 MB
  ushort* Ub  = (ushort*)(base + 38 * MB);       // 8 MB
  ushort* Vb  = (ushort*)(base + 46 * MB);       // 8 MB
  ushort* Vt  = (ushort*)(base + 54 * MB);       // 8 MB
  float*  xb  = (float*)(base + 62 * MB);        // 16 MB
  ushort* ab  = h;                               // reuse: h dead after QKUV gemm

  const size_t DD = 1048576;
  for (int i = 0; i < 2; i++){
    WP wp;
    for (int j = 0; j < 7; j++)
      wp.s[j] = (const float*)d_in[2 + 2 * j] + (size_t)i * DD;
    convert_weights<<<7 * 128, 256, 0, stream>>>(wp, wbf);
    const ushort* Wl = wbf;
    const float* xin = (i == 0) ? seqs : xb;
    ln_kernel<0><<<4096, 256, 0, stream>>>(xin, ln1g + i * D_, ln1b + i * D_, nullptr, h);
    // fused QKUV projection: N = 4096 over slots [Wq,Wk,Wu,Wv]
    P4 io_qkuv = {{Qb, Kb, Ub, Vb}, {bq + i * D_, bk + i * D_, bu + i * D_, bv + i * D_}};
    gemm_k<3, 32><<<1024, 256, 0, stream>>>(h, Wl, io_qkuv, nullptr, nullptr);
    rope_kernel<<<2048, 256, 0, stream>>>(Qb, Kb);
    transpose_v<<<1024, 256, 0, stream>>>(Vb, Vt);
    attn_kernel<<<256, 256, 0, stream>>>(Qb, Kb, Vt, Ub, ab);
    P4 io_o = {{nullptr, nullptr, nullptr, nullptr}, {bo + i * D_, nullptr, nullptr, nullptr}};
    gemm_k<1, 8><<<256, 256, 0, stream>>>(ab, Wl + 4 * DD, io_o, xin, xb);
    ln_kernel<0><<<4096, 256, 0, stream>>>(xb, ln2g + i * D_, ln2b + i * D_, nullptr, h);
    P4 io_1 = {{Qb, nullptr, nullptr, nullptr}, {b1 + i * D_, nullptr, nullptr, nullptr}};
    gemm_k<2, 8><<<256, 256, 0, stream>>>(h, Wl + 5 * DD, io_1, nullptr, nullptr);
    P4 io_2 = {{nullptr, nullptr, nullptr, nullptr}, {b2 + i * D_, nullptr, nullptr, nullptr}};
    gemm_k<1, 8><<<256, 256, 0, stream>>>(Qb, Wl + 6 * DD, io_2, xb, xb);
  }
  ln_kernel<1><<<4096, 256, 0, stream>>>(xb, lnfg, lnfb, (float*)d_out, nullptr);
}

// Round 4
// 581.489 us; speedup vs baseline: 1.0607x; 1.0607x over previous
//
#include <hip/hip_runtime.h>
#include <stdint.h>

typedef __attribute__((ext_vector_type(4))) float f32x4;
typedef __attribute__((ext_vector_type(8))) short s16x8;

#define D_ 1024
#define LQ 2048
#define HH_ 8
#define HD_ 128

static __device__ __forceinline__ float bf2f(ushort u){
  union { unsigned int i; float f; } v; v.i = ((unsigned int)u) << 16; return v.f;
}
static __device__ __forceinline__ ushort f2bf(float f){
  union { float f; unsigned int i; } v; v.f = f;
  unsigned int r = v.i + 0x7fffu + ((v.i >> 16) & 1u);
  return (ushort)(r >> 16);
}

// ---------------- weight fp32 -> bf16 conversion (7 matrices of 1M) --------
struct WP { const float* s[7]; };
__global__ __launch_bounds__(256) void convert_weights(WP wp, ushort* __restrict__ dst){
  int w = blockIdx.x >> 7, blk = blockIdx.x & 127, t = threadIdx.x;
  const float4* s = (const float4*)wp.s[w];
  ushort4* d = (ushort4*)(dst + (size_t)w * 1048576);
  int base = blk * 2048 + t;
  #pragma unroll
  for (int r = 0; r < 8; r++){
    float4 v = s[base + r * 256];
    ushort4 o; o.x = f2bf(v.x); o.y = f2bf(v.y); o.z = f2bf(v.z); o.w = f2bf(v.w);
    d[base + r * 256] = o;
  }
}

// ---------------- layernorm: fp32 in -> bf16 (or fp32) out ------------------
template<int OUTF>
__global__ __launch_bounds__(256) void ln_kernel(const float* __restrict__ x,
    const float* __restrict__ g, const float* __restrict__ bb,
    float* __restrict__ outf, ushort* __restrict__ outb){
  int row = blockIdx.x, t = threadIdx.x;
  const float4* xr = (const float4*)(x + (size_t)row * D_);
  float4 v = xr[t];
  float s = v.x + v.y + v.z + v.w;
  float sq = v.x*v.x + v.y*v.y + v.z*v.z + v.w*v.w;
  #pragma unroll
  for (int o = 32; o; o >>= 1){ s += __shfl_down(s, o, 64); sq += __shfl_down(sq, o, 64); }
  __shared__ float red[8];
  int lane = t & 63, wv = t >> 6;
  if (!lane){ red[wv] = s; red[wv + 4] = sq; }
  __syncthreads();
  float S = red[0] + red[1] + red[2] + red[3];
  float SQ = red[4] + red[5] + red[6] + red[7];
  float m = S * (1.f / 1024.f);
  float var = SQ * (1.f / 1024.f) - m * m;
  float inv = rsqrtf(var + 1e-8f);
  float4 gv = ((const float4*)g)[t], bv = ((const float4*)bb)[t];
  float4 y;
  y.x = (v.x - m) * inv * gv.x + bv.x;
  y.y = (v.y - m) * inv * gv.y + bv.y;
  y.z = (v.z - m) * inv * gv.z + bv.z;
  y.w = (v.w - m) * inv * gv.w + bv.w;
  if (OUTF){
    ((float4*)outf)[(size_t)row * 256 + t] = y;
  } else {
    ushort4 o4; o4.x = f2bf(y.x); o4.y = f2bf(y.y); o4.z = f2bf(y.z); o4.w = f2bf(y.w);
    ((ushort4*)outb)[(size_t)row * 256 + t] = o4;
  }
}

// ---------------- GEMM: out[m,n] = sum_k A[m,k]*W[n,k] (+epilogue) ----------
// EPI: 0 = bias -> bf16 ; 1 = bias + residual -> fp32 ; 2 = bias + p*silu(p) -> bf16
//      3 = QKUV fused (N=4096, select dst/bias by n0>>10; RoPE on Q,K) -> bf16
struct P4 { ushort* d[4]; const float* b[4]; };

template<int EPI, int NB>
__global__ __launch_bounds__(256, 2) void gemm_k(
    const ushort* __restrict__ A, const ushort* __restrict__ W,
    P4 io, const float* __restrict__ resid, float* __restrict__ outf){
  __shared__ ushort As[128 * 32];
  __shared__ ushort Bs[128 * 32];
  int m0 = (blockIdx.x / NB) << 7;
  int n0 = (blockIdx.x % NB) << 7;
  int t = threadIdx.x, lane = t & 63, wv = t >> 6;
  int l15 = lane & 15, q8 = (lane >> 4) * 8;
  int wm = (wv & 1) << 6, wn = (wv >> 1) << 6;
  f32x4 acc[4][4] = {};
  for (int k0 = 0; k0 < 1024; k0 += 32){
    #pragma unroll
    for (int r = 0; r < 2; r++){
      int cb = r * 256 + wv * 64;   // wave-uniform chunk base
      int c = cb + lane;
      int row = c >> 2, kk = (c & 3) << 3;
      const ushort* ga = A + (size_t)(m0 + row) * 1024 + k0 + kk;
      const ushort* gb = W + (size_t)(n0 + row) * 1024 + k0 + kk;
      __builtin_amdgcn_global_load_lds(
          (const __attribute__((address_space(1))) unsigned int*)ga,
          (__attribute__((address_space(3))) unsigned int*)&As[cb * 8], 16, 0, 0);
      __builtin_amdgcn_global_load_lds(
          (const __attribute__((address_space(1))) unsigned int*)gb,
          (__attribute__((address_space(3))) unsigned int*)&Bs[cb * 8], 16, 0, 0);
    }
    __syncthreads();
    s16x8 afr[4], bfr[4];
    #pragma unroll
    for (int mi = 0; mi < 4; mi++) afr[mi] = *(const s16x8*)&As[(wm + mi * 16 + l15) * 32 + q8];
    #pragma unroll
    for (int ni = 0; ni < 4; ni++) bfr[ni] = *(const s16x8*)&Bs[(wn + ni * 16 + l15) * 32 + q8];
    #pragma unroll
    for (int mi = 0; mi < 4; mi++)
      #pragma unroll
      for (int ni = 0; ni < 4; ni++)
        acc[mi][ni] = __builtin_amdgcn_mfma_f32_16x16x32_bf16(afr[mi], bfr[ni], acc[mi][ni], 0, 0, 0);
    __syncthreads();
  }
  int sel = (EPI == 3) ? (n0 >> 10) : 0;
  ushort* dst = io.d[sel];
  const float* bias = io.b[sel];
  int ncol = (EPI == 3) ? (n0 & 1023) : n0;
  int quad = lane >> 4;
  #pragma unroll
  for (int mi = 0; mi < 4; mi++){
    int gm = m0 + wm + mi * 16 + quad * 4;
    #pragma unroll
    for (int ni = 0; ni < 4; ni++){
      int cn = ncol + wn + ni * 16 + l15;
      float bv = bias[cn];
      if (EPI == 3 && sel < 2){
        // fused RoPE: pair (even,odd) cols live in lanes lane^1
        int i2 = (cn & 127) >> 1;
        float freq = __builtin_amdgcn_exp2f(-0.20762050f * (float)i2);  // 10000^(-2i/128)
        int odd = cn & 1;
        #pragma unroll
        for (int r = 0; r < 4; r++){
          float val = acc[mi][ni][r] + bv;
          float pv = __shfl_xor(val, 1, 64);
          int pos = (gm + r) & 2047;
          float ang = (float)pos * freq;
          float sv, cv; __sincosf(ang, &sv, &cv);
          float res = odd ? (pv * sv + val * cv) : (val * cv - pv * sv);
          dst[(size_t)(gm + r) * 1024 + cn] = f2bf(res);
        }
      } else {
        #pragma unroll
        for (int r = 0; r < 4; r++){
          float val = acc[mi][ni][r] + bv;
          size_t o = (size_t)(gm + r) * 1024 + cn;
          if (EPI == 1){ outf[o] = resid[o] + val; }
          else if (EPI == 2){
            float sg = __builtin_amdgcn_rcpf(1.f + __expf(-val));
            dst[o] = f2bf(val * val * sg);
          }
          else { dst[o] = f2bf(val); }
        }
      }
    }
  }
}

// ---------------- V (B,L,H,HD) -> Vt (B,H,HD,L) -----------------------------
__global__ __launch_bounds__(256) void transpose_v(const ushort* __restrict__ Vb, ushort* __restrict__ Vt){
  int bidx = blockIdx.x;                 // 16 bh * 32 lt * 2 dt
  int dt = bidx & 1, lt = (bidx >> 1) & 31, bh = bidx >> 6;
  int b = bh >> 3, hh = bh & 7;
  int l0 = lt << 6, d0 = dt << 6;
  __shared__ ushort tile[64][66];
  int t = threadIdx.x;
  #pragma unroll
  for (int r = 0; r < 8; r++){
    int idx = r * 256 + t;
    int row = idx >> 5, cu = idx & 31;
    unsigned int val = *(const unsigned int*)(Vb + (size_t)(b * LQ + l0 + row) * D_ + hh * HD_ + d0 + cu * 2);
    *(unsigned int*)&tile[row][cu * 2] = val;
  }
  __syncthreads();
  #pragma unroll
  for (int r = 0; r < 8; r++){
    int idx = r * 256 + t;
    int drow = idx >> 5, lu = idx & 31;
    unsigned int val = (unsigned int)tile[lu * 2][drow] | ((unsigned int)tile[lu * 2 + 1][drow] << 16);
    *(unsigned int*)(Vt + ((size_t)(bh * HD_ + d0 + drow)) * LQ + l0 + lu * 2) = val;
  }
}

// ---------------- causal silu-attention, gated by U -------------------------
// out[b,q,h,d] = U * sum_{k<=q} silu(QK^T/sqrt(HD)) * V
// 512 blocks, heavy-first qt ordering; Q fragments in registers; 45 KB LDS
// -> 3 blocks/CU co-resident to overlap barrier/staging stalls.
__global__ __launch_bounds__(256, 3) void attn_kernel(
    const ushort* __restrict__ Q, const ushort* __restrict__ K,
    const ushort* __restrict__ Vt, const ushort* __restrict__ U,
    ushort* __restrict__ Aout){
  __shared__ ushort Ks[64 * 136];
  __shared__ ushort Vs[128 * 72];
  __shared__ ushort Ps[64 * 72];
  int t = threadIdx.x, lane = t & 63, wv = t >> 6;
  int l15 = lane & 15, quad = lane >> 4, q8 = quad * 8;
  int idx = blockIdx.x;
  int bh = idx & 15;
  int qt = (idx < 256) ? (31 - (idx >> 4)) : ((idx - 256) >> 4);
  int b = bh >> 3, hh = bh & 7;
  int q0 = qt << 6;
  const float scale = 0.08838834764831845f;  // 1/sqrt(128)

  // Q fragments directly into registers (A-layout: row=l15, k=quad*8+j)
  s16x8 qf[4];
  const ushort* qbase = Q + (size_t)(b * LQ + q0 + (wv << 4) + l15) * D_ + hh * HD_;
  #pragma unroll
  for (int kd = 0; kd < 4; kd++) qf[kd] = *(const s16x8*)(qbase + kd * 32 + q8);

  f32x4 acc_o[8] = {};
  int nkt = qt + 1;
  for (int kt = 0; kt < nkt; kt++){
    int k0 = kt << 6;
    __syncthreads();
    #pragma unroll
    for (int r = 0; r < 4; r++){
      int c = r * 256 + t, row = c >> 4, ck = c & 15;
      *(s16x8*)&Ks[row * 136 + ck * 8] =
          *(const s16x8*)(K + (size_t)(b * LQ + k0 + row) * D_ + hh * HD_ + ck * 8);
    }
    #pragma unroll
    for (int r = 0; r < 4; r++){
      int c = r * 256 + t, row = c >> 3, ck = c & 7;
      *(s16x8*)&Vs[row * 72 + ck * 8] =
          *(const s16x8*)(Vt + (size_t)(bh * HD_ + row) * LQ + k0 + ck * 8);
    }
    __syncthreads();
    f32x4 sacc[4] = {};
    #pragma unroll
    for (int kd = 0; kd < 4; kd++){
      #pragma unroll
      for (int ni = 0; ni < 4; ni++){
        s16x8 bf = *(const s16x8*)&Ks[(ni * 16 + l15) * 136 + kd * 32 + q8];
        sacc[ni] = __builtin_amdgcn_mfma_f32_16x16x32_bf16(qf[kd], bf, sacc[ni], 0, 0, 0);
      }
    }
    int qg0 = q0 + (wv << 4) + quad * 4;
    #pragma unroll
    for (int ni = 0; ni < 4; ni++){
      int kg = k0 + ni * 16 + l15;
      #pragma unroll
      for (int r = 0; r < 4; r++){
        float s = sacc[ni][r] * scale;
        float p = (kg <= qg0 + r) ? (s * __builtin_amdgcn_rcpf(1.f + __expf(-s))) : 0.f;
        Ps[((wv << 4) + quad * 4 + r) * 72 + ni * 16 + l15] = f2bf(p);
      }
    }
    __syncthreads();
    int prow = (wv << 4) + l15;
    #pragma unroll
    for (int kv = 0; kv < 2; kv++){
      s16x8 af = *(const s16x8*)&Ps[prow * 72 + kv * 32 + q8];
      #pragma unroll
      for (int nt = 0; nt < 8; nt++){
        s16x8 bf = *(const s16x8*)&Vs[(nt * 16 + l15) * 72 + kv * 32 + q8];
        acc_o[nt] = __builtin_amdgcn_mfma_f32_16x16x32_bf16(af, bf, acc_o[nt], 0, 0, 0);
      }
    }
  }
  #pragma unroll
  for (int nt = 0; nt < 8; nt++){
    #pragma unroll
    for (int r = 0; r < 4; r++){
      int qg = q0 + (wv << 4) + quad * 4 + r;
      int dd = nt * 16 + l15;
      size_t oidx = (size_t)(b * LQ + qg) * D_ + hh * HD_ + dd;
      Aout[oidx] = f2bf(acc_o[nt][r] * bf2f(U[oidx]));
    }
  }
}

// ---------------- launcher --------------------------------------------------
extern "C" void kernel_launch(void* const* d_in, const int* in_sizes, int n_in,
                              void* d_out, int out_size, void* d_ws, size_t ws_size,
                              hipStream_t stream){
  const float* seqs = (const float*)d_in[0];
  const float* bq = (const float*)d_in[3];
  const float* bk = (const float*)d_in[5];
  const float* bu = (const float*)d_in[7];
  const float* bv = (const float*)d_in[9];
  const float* bo = (const float*)d_in[11];
  const float* b1 = (const float*)d_in[13];
  const float* b2 = (const float*)d_in[15];
  const float* ln1g = (const float*)d_in[16];
  const float* ln1b = (const float*)d_in[17];
  const float* ln2g = (const float*)d_in[18];
  const float* ln2b = (const float*)d_in[19];
  const float* lnfg = (const float*)d_in[20];
  const float* lnfb = (const float*)d_in[21];

  char* base = (char*)d_ws;
  const size_t MB = 1u << 20;
  if (ws_size < 78 * MB) return;  // defensive
  ushort* wbf = (ushort*)base;                   // 14 MB
  ushort* h   = (ushort*)(base + 14 * MB);       // 8 MB (ln out; reused as attn out)
  ushort* Qb  = (ushort*)(base + 22 * MB);       // 8 MB (also MLP hidden)
  ushort* Kb  = (ushort*)(base + 30 * MB);       // 8 MB
  ushort* Ub  = (ushort*)(base + 38 * MB);       // 8 MB
  ushort* Vb  = (ushort*)(base + 46 * MB);       // 8 MB
  ushort* Vt  = (ushort*)(base + 54 * MB);       // 8 MB
  float*  xb  = (float*)(base + 62 * MB);        // 16 MB
  ushort* ab  = h;

  const size_t DD = 1048576;
  for (int i = 0; i < 2; i++){
    WP wp;
    for (int j = 0; j < 7; j++)
      wp.s[j] = (const float*)d_in[2 + 2 * j] + (size_t)i * DD;
    convert_weights<<<7 * 128, 256, 0, stream>>>(wp, wbf);
    const ushort* Wl = wbf;
    const float* xin = (i == 0) ? seqs : xb;
    ln_kernel<0><<<4096, 256, 0, stream>>>(xin, ln1g + i * D_, ln1b + i * D_, nullptr, h);
    // fused QKUV projection (N=4096) with fused RoPE on Q,K
    P4 io_qkuv = {{Qb, Kb, Ub, Vb}, {bq + i * D_, bk + i * D_, bu + i * D_, bv + i * D_}};
    gemm_k<3, 32><<<1024, 256, 0, stream>>>(h, Wl, io_qkuv, nullptr, nullptr);
    transpose_v<<<1024, 256, 0, stream>>>(Vb, Vt);
    attn_kernel<<<512, 256, 0, stream>>>(Qb, Kb, Vt, Ub, ab);
    P4 io_o = {{nullptr, nullptr, nullptr, nullptr}, {bo + i * D_, nullptr, nullptr, nullptr}};
    gemm_k<1, 8><<<256, 256, 0, stream>>>(ab, Wl + 4 * DD, io_o, xin, xb);
    ln_kernel<0><<<4096, 256, 0, stream>>>(xb, ln2g + i * D_, ln2b + i * D_, nullptr, h);
    P4 io_1 = {{Qb, nullptr, nullptr, nullptr}, {b1 + i * D_, nullptr, nullptr, nullptr}};
    gemm_k<2, 8><<<256, 256, 0, stream>>>(h, Wl + 5 * DD, io_1, nullptr, nullptr);
    P4 io_2 = {{nullptr, nullptr, nullptr, nullptr}, {b2 + i * D_, nullptr, nullptr, nullptr}};
    gemm_k<1, 8><<<256, 256, 0, stream>>>(Qb, Wl + 6 * DD, io_2, xb, xb);
  }
  ln_kernel<1><<<4096, 256, 0, stream>>>(xb, lnfg, lnfb, (float*)d_out, nullptr);
}

// Round 5
// 517.594 us; speedup vs baseline: 1.1916x; 1.1234x over previous
//
#include <hip/hip_runtime.h>
#include <stdint.h>

typedef __attribute__((ext_vector_type(4))) float f32x4;
typedef __attribute__((ext_vector_type(8))) short s16x8;

#define D_ 1024
#define LQ 2048
#define HH_ 8
#define HD_ 128

static __device__ __forceinline__ float bf2f(ushort u){
  union { unsigned int i; float f; } v; v.i = ((unsigned int)u) << 16; return v.f;
}
static __device__ __forceinline__ ushort f2bf(float f){
  union { float f; unsigned int i; } v; v.f = f;
  unsigned int r = v.i + 0x7fffu + ((v.i >> 16) & 1u);
  return (ushort)(r >> 16);
}

// ---------------- weight fp32 -> bf16 conversion (7 matrices of 1M) --------
struct WP { const float* s[7]; };
__global__ __launch_bounds__(256) void convert_weights(WP wp, ushort* __restrict__ dst){
  int w = blockIdx.x >> 7, blk = blockIdx.x & 127, t = threadIdx.x;
  const float4* s = (const float4*)wp.s[w];
  ushort4* d = (ushort4*)(dst + (size_t)w * 1048576);
  int base = blk * 2048 + t;
  #pragma unroll
  for (int r = 0; r < 8; r++){
    float4 v = s[base + r * 256];
    ushort4 o; o.x = f2bf(v.x); o.y = f2bf(v.y); o.z = f2bf(v.z); o.w = f2bf(v.w);
    d[base + r * 256] = o;
  }
}

// ---------------- layernorm: fp32 in -> bf16 (or fp32) out ------------------
template<int OUTF>
__global__ __launch_bounds__(256) void ln_kernel(const float* __restrict__ x,
    const float* __restrict__ g, const float* __restrict__ bb,
    float* __restrict__ outf, ushort* __restrict__ outb){
  int row = blockIdx.x, t = threadIdx.x;
  const float4* xr = (const float4*)(x + (size_t)row * D_);
  float4 v = xr[t];
  float s = v.x + v.y + v.z + v.w;
  float sq = v.x*v.x + v.y*v.y + v.z*v.z + v.w*v.w;
  #pragma unroll
  for (int o = 32; o; o >>= 1){ s += __shfl_down(s, o, 64); sq += __shfl_down(sq, o, 64); }
  __shared__ float red[8];
  int lane = t & 63, wv = t >> 6;
  if (!lane){ red[wv] = s; red[wv + 4] = sq; }
  __syncthreads();
  float S = red[0] + red[1] + red[2] + red[3];
  float SQ = red[4] + red[5] + red[6] + red[7];
  float m = S * (1.f / 1024.f);
  float var = SQ * (1.f / 1024.f) - m * m;
  float inv = rsqrtf(var + 1e-8f);
  float4 gv = ((const float4*)g)[t], bv = ((const float4*)bb)[t];
  float4 y;
  y.x = (v.x - m) * inv * gv.x + bv.x;
  y.y = (v.y - m) * inv * gv.y + bv.y;
  y.z = (v.z - m) * inv * gv.z + bv.z;
  y.w = (v.w - m) * inv * gv.w + bv.w;
  if (OUTF){
    ((float4*)outf)[(size_t)row * 256 + t] = y;
  } else {
    ushort4 o4; o4.x = f2bf(y.x); o4.y = f2bf(y.y); o4.z = f2bf(y.z); o4.w = f2bf(y.w);
    ((ushort4*)outb)[(size_t)row * 256 + t] = o4;
  }
}

// ---------------- GEMM 128x128: QKUV fused (EPI=3) with RoPE ----------------
struct P4 { ushort* d[4]; const float* b[4]; };

template<int EPI, int NB>
__global__ __launch_bounds__(256, 2) void gemm_k(
    const ushort* __restrict__ A, const ushort* __restrict__ W,
    P4 io, const float* __restrict__ resid, float* __restrict__ outf){
  __shared__ ushort As[128 * 32];
  __shared__ ushort Bs[128 * 32];
  int m0 = (blockIdx.x / NB) << 7;
  int n0 = (blockIdx.x % NB) << 7;
  int t = threadIdx.x, lane = t & 63, wv = t >> 6;
  int l15 = lane & 15, q8 = (lane >> 4) * 8;
  int wm = (wv & 1) << 6, wn = (wv >> 1) << 6;
  f32x4 acc[4][4] = {};
  for (int k0 = 0; k0 < 1024; k0 += 32){
    #pragma unroll
    for (int r = 0; r < 2; r++){
      int cb = r * 256 + wv * 64;   // wave-uniform chunk base
      int c = cb + lane;
      int row = c >> 2, kk = (c & 3) << 3;
      const ushort* ga = A + (size_t)(m0 + row) * 1024 + k0 + kk;
      const ushort* gb = W + (size_t)(n0 + row) * 1024 + k0 + kk;
      __builtin_amdgcn_global_load_lds(
          (const __attribute__((address_space(1))) unsigned int*)ga,
          (__attribute__((address_space(3))) unsigned int*)&As[cb * 8], 16, 0, 0);
      __builtin_amdgcn_global_load_lds(
          (const __attribute__((address_space(1))) unsigned int*)gb,
          (__attribute__((address_space(3))) unsigned int*)&Bs[cb * 8], 16, 0, 0);
    }
    __syncthreads();
    s16x8 afr[4], bfr[4];
    #pragma unroll
    for (int mi = 0; mi < 4; mi++) afr[mi] = *(const s16x8*)&As[(wm + mi * 16 + l15) * 32 + q8];
    #pragma unroll
    for (int ni = 0; ni < 4; ni++) bfr[ni] = *(const s16x8*)&Bs[(wn + ni * 16 + l15) * 32 + q8];
    #pragma unroll
    for (int mi = 0; mi < 4; mi++)
      #pragma unroll
      for (int ni = 0; ni < 4; ni++)
        acc[mi][ni] = __builtin_amdgcn_mfma_f32_16x16x32_bf16(afr[mi], bfr[ni], acc[mi][ni], 0, 0, 0);
    __syncthreads();
  }
  int sel = (EPI == 3) ? (n0 >> 10) : 0;
  ushort* dst = io.d[sel];
  const float* bias = io.b[sel];
  int ncol = (EPI == 3) ? (n0 & 1023) : n0;
  int quad = lane >> 4;
  #pragma unroll
  for (int mi = 0; mi < 4; mi++){
    int gm = m0 + wm + mi * 16 + quad * 4;
    #pragma unroll
    for (int ni = 0; ni < 4; ni++){
      int cn = ncol + wn + ni * 16 + l15;
      float bv = bias[cn];
      if (EPI == 3 && sel < 2){
        // fused RoPE: pair (even,odd) cols live in lanes lane^1
        int i2 = (cn & 127) >> 1;
        float freq = __builtin_amdgcn_exp2f(-0.20762050f * (float)i2);  // 10000^(-2i/128)
        int odd = cn & 1;
        #pragma unroll
        for (int r = 0; r < 4; r++){
          float val = acc[mi][ni][r] + bv;
          float pv = __shfl_xor(val, 1, 64);
          int pos = (gm + r) & 2047;
          float ang = (float)pos * freq;
          float sv, cv; __sincosf(ang, &sv, &cv);
          float res = odd ? (pv * sv + val * cv) : (val * cv - pv * sv);
          dst[(size_t)(gm + r) * 1024 + cn] = f2bf(res);
        }
      } else {
        #pragma unroll
        for (int r = 0; r < 4; r++){
          float val = acc[mi][ni][r] + bv;
          size_t o = (size_t)(gm + r) * 1024 + cn;
          if (EPI == 1){ outf[o] = resid[o] + val; }
          else if (EPI == 2){
            float sg = __builtin_amdgcn_rcpf(1.f + __expf(-val));
            dst[o] = f2bf(val * val * sg);
          }
          else { dst[o] = f2bf(val); }
        }
      }
    }
  }
}

// ---------------- GEMM 64x128 tile (512 blocks -> 2/CU) ---------------------
// EPI: 1 = bias + residual -> fp32 ; 2 = bias + p*silu(p) -> bf16
template<int EPI>
__global__ __launch_bounds__(256, 2) void gemm_k2(
    const ushort* __restrict__ A, const ushort* __restrict__ W,
    const float* __restrict__ bias, ushort* __restrict__ dst,
    const float* __restrict__ resid, float* __restrict__ outf){
  __shared__ ushort As[64 * 32];
  __shared__ ushort Bs[128 * 32];
  int m0 = (blockIdx.x >> 3) << 6;
  int n0 = (blockIdx.x & 7) << 7;
  int t = threadIdx.x, lane = t & 63, wv = t >> 6;
  int l15 = lane & 15, q8 = (lane >> 4) * 8;
  int wm = (wv & 1) << 5, wn = (wv >> 1) << 6;
  f32x4 acc[2][4] = {};
  for (int k0 = 0; k0 < 1024; k0 += 32){
    #pragma unroll
    for (int r = 0; r < 3; r++){
      int cb = r * 256 + wv * 64;
      int c = cb + lane;
      int kk = (c & 3) << 3;
      if (r == 0){
        int row = c >> 2;               // A rows 0..63
        __builtin_amdgcn_global_load_lds(
            (const __attribute__((address_space(1))) unsigned int*)(A + (size_t)(m0 + row) * 1024 + k0 + kk),
            (__attribute__((address_space(3))) unsigned int*)&As[cb * 8], 16, 0, 0);
      } else {
        int row = (c >> 2) - 64;        // B rows 0..127
        __builtin_amdgcn_global_load_lds(
            (const __attribute__((address_space(1))) unsigned int*)(W + (size_t)(n0 + row) * 1024 + k0 + kk),
            (__attribute__((address_space(3))) unsigned int*)&Bs[(cb - 256) * 8], 16, 0, 0);
      }
    }
    __syncthreads();
    s16x8 afr[2], bfr[4];
    #pragma unroll
    for (int mi = 0; mi < 2; mi++) afr[mi] = *(const s16x8*)&As[(wm + mi * 16 + l15) * 32 + q8];
    #pragma unroll
    for (int ni = 0; ni < 4; ni++) bfr[ni] = *(const s16x8*)&Bs[(wn + ni * 16 + l15) * 32 + q8];
    #pragma unroll
    for (int mi = 0; mi < 2; mi++)
      #pragma unroll
      for (int ni = 0; ni < 4; ni++)
        acc[mi][ni] = __builtin_amdgcn_mfma_f32_16x16x32_bf16(afr[mi], bfr[ni], acc[mi][ni], 0, 0, 0);
    __syncthreads();
  }
  int quad = lane >> 4;
  #pragma unroll
  for (int mi = 0; mi < 2; mi++){
    int gm = m0 + wm + mi * 16 + quad * 4;
    #pragma unroll
    for (int ni = 0; ni < 4; ni++){
      int cn = n0 + wn + ni * 16 + l15;
      float bv = bias[cn];
      #pragma unroll
      for (int r = 0; r < 4; r++){
        float val = acc[mi][ni][r] + bv;
        size_t o = (size_t)(gm + r) * 1024 + cn;
        if (EPI == 1){ outf[o] = resid[o] + val; }
        else {
          float sg = __builtin_amdgcn_rcpf(1.f + __expf(-val));
          dst[o] = f2bf(val * val * sg);
        }
      }
    }
  }
}

// ---------------- V (B,L,H,HD) -> Vt (B,H,HD,L) -----------------------------
__global__ __launch_bounds__(256) void transpose_v(const ushort* __restrict__ Vb, ushort* __restrict__ Vt){
  int bidx = blockIdx.x;                 // 16 bh * 32 lt * 2 dt
  int dt = bidx & 1, lt = (bidx >> 1) & 31, bh = bidx >> 6;
  int b = bh >> 3, hh = bh & 7;
  int l0 = lt << 6, d0 = dt << 6;
  __shared__ ushort tile[64][66];
  int t = threadIdx.x;
  #pragma unroll
  for (int r = 0; r < 8; r++){
    int idx = r * 256 + t;
    int row = idx >> 5, cu = idx & 31;
    unsigned int val = *(const unsigned int*)(Vb + (size_t)(b * LQ + l0 + row) * D_ + hh * HD_ + d0 + cu * 2);
    *(unsigned int*)&tile[row][cu * 2] = val;
  }
  __syncthreads();
  #pragma unroll
  for (int r = 0; r < 8; r++){
    int idx = r * 256 + t;
    int drow = idx >> 5, lu = idx & 31;
    unsigned int val = (unsigned int)tile[lu * 2][drow] | ((unsigned int)tile[lu * 2 + 1][drow] << 16);
    *(unsigned int*)(Vt + ((size_t)(bh * HD_ + d0 + drow)) * LQ + l0 + lu * 2) = val;
  }
}

// ---------------- causal silu-attention, split-K ----------------------------
// Partial O = sum over a k-range of silu(QK^T/sqrt(HD)) * V, stored bf16.
// 1024 blocks: (bh, qt, half); heavy-first slot ordering; <=16 iters/block;
// 45 KB LDS -> 3 blocks/CU; 2 barriers/iter (Ps is wave-private).
__global__ __launch_bounds__(256, 3) void attn_kernel(
    const ushort* __restrict__ Q, const ushort* __restrict__ K,
    const ushort* __restrict__ Vt,
    ushort* __restrict__ Po0, ushort* __restrict__ Po1){
  __shared__ ushort Ks[64 * 136];
  __shared__ ushort Vs[128 * 72];
  __shared__ ushort Ps[64 * 72];
  int t = threadIdx.x, lane = t & 63, wv = t >> 6;
  int l15 = lane & 15, quad = lane >> 4, q8 = quad * 8;
  int idx = blockIdx.x;
  int bh = idx & 15;
  int slot = idx >> 4;                 // 0..63, heavy-first
  int qt = 31 - (slot >> 1);
  int half = slot & 1;
  int n = qt + 1;
  int c0 = (n + 1) >> 1;               // half0: [0,c0), half1: [c0,n)
  int klo = half ? c0 : 0;
  int khi = half ? n : c0;
  if (klo >= khi) return;              // qt=0, half1: empty
  int b = bh >> 3, hh = bh & 7;
  int q0 = qt << 6;
  const float scale = 0.08838834764831845f;  // 1/sqrt(128)

  // Q fragments directly into registers (A-layout: row=l15, k=quad*8+j)
  s16x8 qf[4];
  const ushort* qbase = Q + (size_t)(b * LQ + q0 + (wv << 4) + l15) * D_ + hh * HD_;
  #pragma unroll
  for (int kd = 0; kd < 4; kd++) qf[kd] = *(const s16x8*)(qbase + kd * 32 + q8);

  f32x4 acc_o[8] = {};
  for (int kt = klo; kt < khi; kt++){
    int k0 = kt << 6;
    __syncthreads();                   // all waves done reading prev Ks/Vs
    #pragma unroll
    for (int r = 0; r < 4; r++){
      int c = r * 256 + t, row = c >> 4, ck = c & 15;
      *(s16x8*)&Ks[row * 136 + ck * 8] =
          *(const s16x8*)(K + (size_t)(b * LQ + k0 + row) * D_ + hh * HD_ + ck * 8);
    }
    #pragma unroll
    for (int r = 0; r < 4; r++){
      int c = r * 256 + t, row = c >> 3, ck = c & 7;
      *(s16x8*)&Vs[row * 72 + ck * 8] =
          *(const s16x8*)(Vt + (size_t)(bh * HD_ + row) * LQ + k0 + ck * 8);
    }
    __syncthreads();                   // staging visible
    f32x4 sacc[4] = {};
    #pragma unroll
    for (int kd = 0; kd < 4; kd++){
      #pragma unroll
      for (int ni = 0; ni < 4; ni++){
        s16x8 bf = *(const s16x8*)&Ks[(ni * 16 + l15) * 136 + kd * 32 + q8];
        sacc[ni] = __builtin_amdgcn_mfma_f32_16x16x32_bf16(qf[kd], bf, sacc[ni], 0, 0, 0);
      }
    }
    int qg0 = q0 + (wv << 4) + quad * 4;
    #pragma unroll
    for (int ni = 0; ni < 4; ni++){
      int kg = k0 + ni * 16 + l15;
      #pragma unroll
      for (int r = 0; r < 4; r++){
        float s = sacc[ni][r] * scale;
        float p = (kg <= qg0 + r) ? (s * __builtin_amdgcn_rcpf(1.f + __expf(-s))) : 0.f;
        Ps[((wv << 4) + quad * 4 + r) * 72 + ni * 16 + l15] = f2bf(p);
      }
    }
    // no barrier: Ps rows [wv*16, wv*16+16) are written & read by this wave only
    int prow = (wv << 4) + l15;
    #pragma unroll
    for (int kv = 0; kv < 2; kv++){
      s16x8 af = *(const s16x8*)&Ps[prow * 72 + kv * 32 + q8];
      #pragma unroll
      for (int nt = 0; nt < 8; nt++){
        s16x8 bf = *(const s16x8*)&Vs[(nt * 16 + l15) * 72 + kv * 32 + q8];
        acc_o[nt] = __builtin_amdgcn_mfma_f32_16x16x32_bf16(af, bf, acc_o[nt], 0, 0, 0);
      }
    }
  }
  ushort* Po = half ? Po1 : Po0;
  #pragma unroll
  for (int nt = 0; nt < 8; nt++){
    #pragma unroll
    for (int r = 0; r < 4; r++){
      int qg = q0 + (wv << 4) + quad * 4 + r;
      int dd = nt * 16 + l15;
      Po[(size_t)(b * LQ + qg) * D_ + hh * HD_ + dd] = f2bf(acc_o[nt][r]);
    }
  }
}

// ---------------- attn partial reduce: (P0 + P1[q>=64]) * U -> bf16 ---------
__global__ __launch_bounds__(256) void attn_reduce(
    const ushort* __restrict__ Po0, const ushort* __restrict__ Po1,
    const ushort* __restrict__ U, ushort* __restrict__ Aout){
  int i = (blockIdx.x * 256 + threadIdx.x) * 4;   // 4M elems total
  int l = (i >> 10) & 2047;
  ushort4 p0 = *(const ushort4*)(Po0 + i);
  float v0 = bf2f(p0.x), v1 = bf2f(p0.y), v2 = bf2f(p0.z), v3 = bf2f(p0.w);
  if (l >= 64){
    ushort4 p1 = *(const ushort4*)(Po1 + i);
    v0 += bf2f(p1.x); v1 += bf2f(p1.y); v2 += bf2f(p1.z); v3 += bf2f(p1.w);
  }
  ushort4 u = *(const ushort4*)(U + i);
  ushort4 o;
  o.x = f2bf(v0 * bf2f(u.x)); o.y = f2bf(v1 * bf2f(u.y));
  o.z = f2bf(v2 * bf2f(u.z)); o.w = f2bf(v3 * bf2f(u.w));
  *(ushort4*)(Aout + i) = o;
}

// ---------------- launcher --------------------------------------------------
extern "C" void kernel_launch(void* const* d_in, const int* in_sizes, int n_in,
                              void* d_out, int out_size, void* d_ws, size_t ws_size,
                              hipStream_t stream){
  const float* seqs = (const float*)d_in[0];
  const float* bq = (const float*)d_in[3];
  const float* bk = (const float*)d_in[5];
  const float* bu = (const float*)d_in[7];
  const float* bv = (const float*)d_in[9];
  const float* bo = (const float*)d_in[11];
  const float* b1 = (const float*)d_in[13];
  const float* b2 = (const float*)d_in[15];
  const float* ln1g = (const float*)d_in[16];
  const float* ln1b = (const float*)d_in[17];
  const float* ln2g = (const float*)d_in[18];
  const float* ln2b = (const float*)d_in[19];
  const float* lnfg = (const float*)d_in[20];
  const float* lnfb = (const float*)d_in[21];

  char* base = (char*)d_ws;
  const size_t MB = 1u << 20;
  if (ws_size < 78 * MB) return;  // defensive
  ushort* wbf = (ushort*)base;                   // 14 MB
  ushort* h   = (ushort*)(base + 14 * MB);       // 8 MB (ln out; attn Po0; attn out)
  ushort* Qb  = (ushort*)(base + 22 * MB);       // 8 MB (also MLP hidden)
  ushort* Kb  = (ushort*)(base + 30 * MB);       // 8 MB
  ushort* Ub  = (ushort*)(base + 38 * MB);       // 8 MB
  ushort* Vb  = (ushort*)(base + 46 * MB);       // 8 MB (attn Po1 after transpose)
  ushort* Vt  = (ushort*)(base + 54 * MB);       // 8 MB
  float*  xb  = (float*)(base + 62 * MB);        // 16 MB
  ushort* ab  = h;

  const size_t DD = 1048576;
  for (int i = 0; i < 2; i++){
    WP wp;
    for (int j = 0; j < 7; j++)
      wp.s[j] = (const float*)d_in[2 + 2 * j] + (size_t)i * DD;
    convert_weights<<<7 * 128, 256, 0, stream>>>(wp, wbf);
    const ushort* Wl = wbf;
    const float* xin = (i == 0) ? seqs : xb;
    ln_kernel<0><<<4096, 256, 0, stream>>>(xin, ln1g + i * D_, ln1b + i * D_, nullptr, h);
    // fused QKUV projection (N=4096) with fused RoPE on Q,K
    P4 io_qkuv = {{Qb, Kb, Ub, Vb}, {bq + i * D_, bk + i * D_, bu + i * D_, bv + i * D_}};
    gemm_k<3, 32><<<1024, 256, 0, stream>>>(h, Wl, io_qkuv, nullptr, nullptr);
    transpose_v<<<1024, 256, 0, stream>>>(Vb, Vt);
    attn_kernel<<<1024, 256, 0, stream>>>(Qb, Kb, Vt, ab, Vb);
    attn_reduce<<<4096, 256, 0, stream>>>(ab, Vb, Ub, ab);
    gemm_k2<1><<<512, 256, 0, stream>>>(ab, Wl + 4 * DD, bo + i * D_, nullptr, xin, xb);
    ln_kernel<0><<<4096, 256, 0, stream>>>(xb, ln2g + i * D_, ln2b + i * D_, nullptr, h);
    gemm_k2<2><<<512, 256, 0, stream>>>(h, Wl + 5 * DD, b1 + i * D_, Qb, nullptr, nullptr);
    gemm_k2<1><<<512, 256, 0, stream>>>(Qb, Wl + 6 * DD, b2 + i * D_, nullptr, xb, xb);
  }
  ln_kernel<1><<<4096, 256, 0, stream>>>(xb, lnfg, lnfb, (float*)d_out, nullptr);
}

// Round 6
// 505.207 us; speedup vs baseline: 1.2208x; 1.0245x over previous
//
#include <hip/hip_runtime.h>
#include <stdint.h>

typedef __attribute__((ext_vector_type(4))) float f32x4;
typedef __attribute__((ext_vector_type(8))) short s16x8;

#define D_ 1024
#define LQ 2048
#define HH_ 8
#define HD_ 128

static __device__ __forceinline__ float bf2f(ushort u){
  union { unsigned int i; float f; } v; v.i = ((unsigned int)u) << 16; return v.f;
}
static __device__ __forceinline__ ushort f2bf(float f){
  union { float f; unsigned int i; } v; v.f = f;
  unsigned int r = v.i + 0x7fffu + ((v.i >> 16) & 1u);
  return (ushort)(r >> 16);
}

// ---------------- weight fp32 -> bf16 conversion (7 matrices of 1M) --------
struct WP { const float* s[7]; };
__global__ __launch_bounds__(256) void convert_weights(WP wp, ushort* __restrict__ dst){
  int w = blockIdx.x >> 7, blk = blockIdx.x & 127, t = threadIdx.x;
  const float4* s = (const float4*)wp.s[w];
  ushort4* d = (ushort4*)(dst + (size_t)w * 1048576);
  int base = blk * 2048 + t;
  #pragma unroll
  for (int r = 0; r < 8; r++){
    float4 v = s[base + r * 256];
    ushort4 o; o.x = f2bf(v.x); o.y = f2bf(v.y); o.z = f2bf(v.z); o.w = f2bf(v.w);
    d[base + r * 256] = o;
  }
}

// ---------------- layernorm: fp32 in -> bf16 (or fp32) out ------------------
template<int OUTF>
__global__ __launch_bounds__(256) void ln_kernel(const float* __restrict__ x,
    const float* __restrict__ g, const float* __restrict__ bb,
    float* __restrict__ outf, ushort* __restrict__ outb){
  int row = blockIdx.x, t = threadIdx.x;
  const float4* xr = (const float4*)(x + (size_t)row * D_);
  float4 v = xr[t];
  float s = v.x + v.y + v.z + v.w;
  float sq = v.x*v.x + v.y*v.y + v.z*v.z + v.w*v.w;
  #pragma unroll
  for (int o = 32; o; o >>= 1){ s += __shfl_down(s, o, 64); sq += __shfl_down(sq, o, 64); }
  __shared__ float red[8];
  int lane = t & 63, wv = t >> 6;
  if (!lane){ red[wv] = s; red[wv + 4] = sq; }
  __syncthreads();
  float S = red[0] + red[1] + red[2] + red[3];
  float SQ = red[4] + red[5] + red[6] + red[7];
  float m = S * (1.f / 1024.f);
  float var = SQ * (1.f / 1024.f) - m * m;
  float inv = rsqrtf(var + 1e-8f);
  float4 gv = ((const float4*)g)[t], bv = ((const float4*)bb)[t];
  float4 y;
  y.x = (v.x - m) * inv * gv.x + bv.x;
  y.y = (v.y - m) * inv * gv.y + bv.y;
  y.z = (v.z - m) * inv * gv.z + bv.z;
  y.w = (v.w - m) * inv * gv.w + bv.w;
  if (OUTF){
    ((float4*)outf)[(size_t)row * 256 + t] = y;
  } else {
    ushort4 o4; o4.x = f2bf(y.x); o4.y = f2bf(y.y); o4.z = f2bf(y.z); o4.w = f2bf(y.w);
    ((ushort4*)outb)[(size_t)row * 256 + t] = o4;
  }
}

// ---------------- GEMM 128x128, BK=64, swizzled LDS -------------------------
// LDS slot (row, j) holds global k-chunk (j ^ (row&7)); fragment reads slot
// ((kd*4+quad) ^ (row&7)) -> 2-way banking (free) instead of 8-way.
// EPI: 3 = QKUV fused (N=4096, dst/bias by n0>>10; RoPE on Q,K) -> bf16
struct P4 { ushort* d[4]; const float* b[4]; };

template<int EPI, int NB>
__global__ __launch_bounds__(256, 2) void gemm_k(
    const ushort* __restrict__ A, const ushort* __restrict__ W,
    P4 io, const float* __restrict__ resid, float* __restrict__ outf){
  __shared__ ushort As[128 * 64];
  __shared__ ushort Bs[128 * 64];
  int m0 = (blockIdx.x / NB) << 7;
  int n0 = (blockIdx.x % NB) << 7;
  int t = threadIdx.x, lane = t & 63, wv = t >> 6;
  int l15 = lane & 15, quad = lane >> 4;
  int wm = (wv & 1) << 6, wn = (wv >> 1) << 6;
  f32x4 acc[4][4] = {};
  for (int k0 = 0; k0 < 1024; k0 += 64){
    #pragma unroll
    for (int r = 0; r < 4; r++){
      int cb = r * 256 + wv * 64;      // wave-uniform chunk base
      int c = cb + lane;               // chunk id 0..1023
      int row = c >> 3, j = c & 7;
      int kk = ((j ^ (row & 7)) << 3); // swizzled global k-chunk
      __builtin_amdgcn_global_load_lds(
          (const __attribute__((address_space(1))) unsigned int*)(A + (size_t)(m0 + row) * 1024 + k0 + kk),
          (__attribute__((address_space(3))) unsigned int*)&As[cb * 8], 16, 0, 0);
      __builtin_amdgcn_global_load_lds(
          (const __attribute__((address_space(1))) unsigned int*)(W + (size_t)(n0 + row) * 1024 + k0 + kk),
          (__attribute__((address_space(3))) unsigned int*)&Bs[cb * 8], 16, 0, 0);
    }
    __syncthreads();
    #pragma unroll
    for (int kd = 0; kd < 2; kd++){
      s16x8 afr[4], bfr[4];
      #pragma unroll
      for (int mi = 0; mi < 4; mi++){
        int R = wm + mi * 16 + l15;
        afr[mi] = *(const s16x8*)&As[R * 64 + (((kd << 2) | quad) ^ (R & 7)) * 8];
      }
      #pragma unroll
      for (int ni = 0; ni < 4; ni++){
        int R = wn + ni * 16 + l15;
        bfr[ni] = *(const s16x8*)&Bs[R * 64 + (((kd << 2) | quad) ^ (R & 7)) * 8];
      }
      #pragma unroll
      for (int mi = 0; mi < 4; mi++)
        #pragma unroll
        for (int ni = 0; ni < 4; ni++)
          acc[mi][ni] = __builtin_amdgcn_mfma_f32_16x16x32_bf16(afr[mi], bfr[ni], acc[mi][ni], 0, 0, 0);
    }
    __syncthreads();
  }
  int sel = (EPI == 3) ? (n0 >> 10) : 0;
  ushort* dst = io.d[sel];
  const float* bias = io.b[sel];
  int ncol = (EPI == 3) ? (n0 & 1023) : n0;
  #pragma unroll
  for (int mi = 0; mi < 4; mi++){
    int gm = m0 + wm + mi * 16 + quad * 4;
    #pragma unroll
    for (int ni = 0; ni < 4; ni++){
      int cn = ncol + wn + ni * 16 + l15;
      float bv = bias[cn];
      if (EPI == 3 && sel < 2){
        // fused RoPE: pair (even,odd) cols live in lanes lane^1
        int i2 = (cn & 127) >> 1;
        float freq = __builtin_amdgcn_exp2f(-0.20762050f * (float)i2);  // 10000^(-2i/128)
        int odd = cn & 1;
        #pragma unroll
        for (int r = 0; r < 4; r++){
          float val = acc[mi][ni][r] + bv;
          float pv = __shfl_xor(val, 1, 64);
          int pos = (gm + r) & 2047;
          float ang = (float)pos * freq;
          float sv, cv; __sincosf(ang, &sv, &cv);
          float res = odd ? (pv * sv + val * cv) : (val * cv - pv * sv);
          dst[(size_t)(gm + r) * 1024 + cn] = f2bf(res);
        }
      } else {
        #pragma unroll
        for (int r = 0; r < 4; r++){
          float val = acc[mi][ni][r] + bv;
          size_t o = (size_t)(gm + r) * 1024 + cn;
          if (EPI == 1){ outf[o] = resid[o] + val; }
          else if (EPI == 2){
            float sg = __builtin_amdgcn_rcpf(1.f + __expf(-val));
            dst[o] = f2bf(val * val * sg);
          }
          else { dst[o] = f2bf(val); }
        }
      }
    }
  }
}

// ---------------- GEMM 64x128 tile, BK=64, swizzled (512 blocks) ------------
// EPI: 1 = bias + residual -> fp32 ; 2 = bias + p*silu(p) -> bf16
template<int EPI>
__global__ __launch_bounds__(256, 2) void gemm_k2(
    const ushort* __restrict__ A, const ushort* __restrict__ W,
    const float* __restrict__ bias, ushort* __restrict__ dst,
    const float* __restrict__ resid, float* __restrict__ outf){
  __shared__ ushort As[64 * 64];
  __shared__ ushort Bs[128 * 64];
  int m0 = (blockIdx.x >> 3) << 6;
  int n0 = (blockIdx.x & 7) << 7;
  int t = threadIdx.x, lane = t & 63, wv = t >> 6;
  int l15 = lane & 15, quad = lane >> 4;
  int wm = (wv & 1) << 5, wn = (wv >> 1) << 6;
  f32x4 acc[2][4] = {};
  for (int k0 = 0; k0 < 1024; k0 += 64){
    #pragma unroll
    for (int r = 0; r < 6; r++){
      int cb = (r < 2 ? r * 256 : (r - 2) * 256) + wv * 64;
      int c = cb + lane;
      int row = c >> 3, j = c & 7;
      int kk = ((j ^ (row & 7)) << 3);
      if (r < 2){
        __builtin_amdgcn_global_load_lds(
            (const __attribute__((address_space(1))) unsigned int*)(A + (size_t)(m0 + row) * 1024 + k0 + kk),
            (__attribute__((address_space(3))) unsigned int*)&As[cb * 8], 16, 0, 0);
      } else {
        __builtin_amdgcn_global_load_lds(
            (const __attribute__((address_space(1))) unsigned int*)(W + (size_t)(n0 + row) * 1024 + k0 + kk),
            (__attribute__((address_space(3))) unsigned int*)&Bs[cb * 8], 16, 0, 0);
      }
    }
    __syncthreads();
    #pragma unroll
    for (int kd = 0; kd < 2; kd++){
      s16x8 afr[2], bfr[4];
      #pragma unroll
      for (int mi = 0; mi < 2; mi++){
        int R = wm + mi * 16 + l15;
        afr[mi] = *(const s16x8*)&As[R * 64 + (((kd << 2) | quad) ^ (R & 7)) * 8];
      }
      #pragma unroll
      for (int ni = 0; ni < 4; ni++){
        int R = wn + ni * 16 + l15;
        bfr[ni] = *(const s16x8*)&Bs[R * 64 + (((kd << 2) | quad) ^ (R & 7)) * 8];
      }
      #pragma unroll
      for (int mi = 0; mi < 2; mi++)
        #pragma unroll
        for (int ni = 0; ni < 4; ni++)
          acc[mi][ni] = __builtin_amdgcn_mfma_f32_16x16x32_bf16(afr[mi], bfr[ni], acc[mi][ni], 0, 0, 0);
    }
    __syncthreads();
  }
  #pragma unroll
  for (int mi = 0; mi < 2; mi++){
    int gm = m0 + wm + mi * 16 + quad * 4;
    #pragma unroll
    for (int ni = 0; ni < 4; ni++){
      int cn = n0 + wn + ni * 16 + l15;
      float bv = bias[cn];
      #pragma unroll
      for (int r = 0; r < 4; r++){
        float val = acc[mi][ni][r] + bv;
        size_t o = (size_t)(gm + r) * 1024 + cn;
        if (EPI == 1){ outf[o] = resid[o] + val; }
        else {
          float sg = __builtin_amdgcn_rcpf(1.f + __expf(-val));
          dst[o] = f2bf(val * val * sg);
        }
      }
    }
  }
}

// ---------------- V (B,L,H,HD) -> Vt (B,H,HD,L) -----------------------------
__global__ __launch_bounds__(256) void transpose_v(const ushort* __restrict__ Vb, ushort* __restrict__ Vt){
  int bidx = blockIdx.x;                 // 16 bh * 32 lt * 2 dt
  int dt = bidx & 1, lt = (bidx >> 1) & 31, bh = bidx >> 6;
  int b = bh >> 3, hh = bh & 7;
  int l0 = lt << 6, d0 = dt << 6;
  __shared__ ushort tile[64][66];
  int t = threadIdx.x;
  #pragma unroll
  for (int r = 0; r < 8; r++){
    int idx = r * 256 + t;
    int row = idx >> 5, cu = idx & 31;
    unsigned int val = *(const unsigned int*)(Vb + (size_t)(b * LQ + l0 + row) * D_ + hh * HD_ + d0 + cu * 2);
    *(unsigned int*)&tile[row][cu * 2] = val;
  }
  __syncthreads();
  #pragma unroll
  for (int r = 0; r < 8; r++){
    int idx = r * 256 + t;
    int drow = idx >> 5, lu = idx & 31;
    unsigned int val = (unsigned int)tile[lu * 2][drow] | ((unsigned int)tile[lu * 2 + 1][drow] << 16);
    *(unsigned int*)(Vt + ((size_t)(bh * HD_ + d0 + drow)) * LQ + l0 + lu * 2) = val;
  }
}

// ---------------- causal silu-attention, split-K ----------------------------
// Partial O = sum over a k-range of silu(QK^T/sqrt(HD)) * V, stored bf16.
// 1024 blocks: (bh, qt, half); heavy-first slot ordering; <=16 iters/block;
// 45 KB LDS -> 3 blocks/CU; 2 barriers/iter (Ps is wave-private).
__global__ __launch_bounds__(256, 3) void attn_kernel(
    const ushort* __restrict__ Q, const ushort* __restrict__ K,
    const ushort* __restrict__ Vt,
    ushort* __restrict__ Po0, ushort* __restrict__ Po1){
  __shared__ ushort Ks[64 * 136];
  __shared__ ushort Vs[128 * 72];
  __shared__ ushort Ps[64 * 72];
  int t = threadIdx.x, lane = t & 63, wv = t >> 6;
  int l15 = lane & 15, quad = lane >> 4, q8 = quad * 8;
  int idx = blockIdx.x;
  int bh = idx & 15;
  int slot = idx >> 4;                 // 0..63, heavy-first
  int qt = 31 - (slot >> 1);
  int half = slot & 1;
  int n = qt + 1;
  int c0 = (n + 1) >> 1;               // half0: [0,c0), half1: [c0,n)
  int klo = half ? c0 : 0;
  int khi = half ? n : c0;
  if (klo >= khi) return;              // qt=0, half1: empty
  int b = bh >> 3, hh = bh & 7;
  int q0 = qt << 6;
  const float scale = 0.08838834764831845f;  // 1/sqrt(128)

  // Q fragments directly into registers (A-layout: row=l15, k=quad*8+j)
  s16x8 qf[4];
  const ushort* qbase = Q + (size_t)(b * LQ + q0 + (wv << 4) + l15) * D_ + hh * HD_;
  #pragma unroll
  for (int kd = 0; kd < 4; kd++) qf[kd] = *(const s16x8*)(qbase + kd * 32 + q8);

  f32x4 acc_o[8] = {};
  for (int kt = klo; kt < khi; kt++){
    int k0 = kt << 6;
    __syncthreads();                   // all waves done reading prev Ks/Vs
    #pragma unroll
    for (int r = 0; r < 4; r++){
      int c = r * 256 + t, row = c >> 4, ck = c & 15;
      *(s16x8*)&Ks[row * 136 + ck * 8] =
          *(const s16x8*)(K + (size_t)(b * LQ + k0 + row) * D_ + hh * HD_ + ck * 8);
    }
    #pragma unroll
    for (int r = 0; r < 4; r++){
      int c = r * 256 + t, row = c >> 3, ck = c & 7;
      *(s16x8*)&Vs[row * 72 + ck * 8] =
          *(const s16x8*)(Vt + (size_t)(bh * HD_ + row) * LQ + k0 + ck * 8);
    }
    __syncthreads();                   // staging visible
    f32x4 sacc[4] = {};
    #pragma unroll
    for (int kd = 0; kd < 4; kd++){
      #pragma unroll
      for (int ni = 0; ni < 4; ni++){
        s16x8 bf = *(const s16x8*)&Ks[(ni * 16 + l15) * 136 + kd * 32 + q8];
        sacc[ni] = __builtin_amdgcn_mfma_f32_16x16x32_bf16(qf[kd], bf, sacc[ni], 0, 0, 0);
      }
    }
    int qg0 = q0 + (wv << 4) + quad * 4;
    #pragma unroll
    for (int ni = 0; ni < 4; ni++){
      int kg = k0 + ni * 16 + l15;
      #pragma unroll
      for (int r = 0; r < 4; r++){
        float s = sacc[ni][r] * scale;
        float p = (kg <= qg0 + r) ? (s * __builtin_amdgcn_rcpf(1.f + __expf(-s))) : 0.f;
        Ps[((wv << 4) + quad * 4 + r) * 72 + ni * 16 + l15] = f2bf(p);
      }
    }
    // no barrier: Ps rows [wv*16, wv*16+16) are written & read by this wave only
    int prow = (wv << 4) + l15;
    #pragma unroll
    for (int kv = 0; kv < 2; kv++){
      s16x8 af = *(const s16x8*)&Ps[prow * 72 + kv * 32 + q8];
      #pragma unroll
      for (int nt = 0; nt < 8; nt++){
        s16x8 bf = *(const s16x8*)&Vs[(nt * 16 + l15) * 72 + kv * 32 + q8];
        acc_o[nt] = __builtin_amdgcn_mfma_f32_16x16x32_bf16(af, bf, acc_o[nt], 0, 0, 0);
      }
    }
  }
  ushort* Po = half ? Po1 : Po0;
  #pragma unroll
  for (int nt = 0; nt < 8; nt++){
    #pragma unroll
    for (int r = 0; r < 4; r++){
      int qg = q0 + (wv << 4) + quad * 4 + r;
      int dd = nt * 16 + l15;
      Po[(size_t)(b * LQ + qg) * D_ + hh * HD_ + dd] = f2bf(acc_o[nt][r]);
    }
  }
}

// ---------------- attn partial reduce: (P0 + P1[q>=64]) * U -> bf16 ---------
__global__ __launch_bounds__(256) void attn_reduce(
    const ushort* __restrict__ Po0, const ushort* __restrict__ Po1,
    const ushort* __restrict__ U, ushort* __restrict__ Aout){
  int i = (blockIdx.x * 256 + threadIdx.x) * 4;   // 4M elems total
  int l = (i >> 10) & 2047;
  ushort4 p0 = *(const ushort4*)(Po0 + i);
  float v0 = bf2f(p0.x), v1 = bf2f(p0.y), v2 = bf2f(p0.z), v3 = bf2f(p0.w);
  if (l >= 64){
    ushort4 p1 = *(const ushort4*)(Po1 + i);
    v0 += bf2f(p1.x); v1 += bf2f(p1.y); v2 += bf2f(p1.z); v3 += bf2f(p1.w);
  }
  ushort4 u = *(const ushort4*)(U + i);
  ushort4 o;
  o.x = f2bf(v0 * bf2f(u.x)); o.y = f2bf(v1 * bf2f(u.y));
  o.z = f2bf(v2 * bf2f(u.z)); o.w = f2bf(v3 * bf2f(u.w));
  *(ushort4*)(Aout + i) = o;
}

// ---------------- launcher --------------------------------------------------
extern "C" void kernel_launch(void* const* d_in, const int* in_sizes, int n_in,
                              void* d_out, int out_size, void* d_ws, size_t ws_size,
                              hipStream_t stream){
  const float* seqs = (const float*)d_in[0];
  const float* bq = (const float*)d_in[3];
  const float* bk = (const float*)d_in[5];
  const float* bu = (const float*)d_in[7];
  const float* bv = (const float*)d_in[9];
  const float* bo = (const float*)d_in[11];
  const float* b1 = (const float*)d_in[13];
  const float* b2 = (const float*)d_in[15];
  const float* ln1g = (const float*)d_in[16];
  const float* ln1b = (const float*)d_in[17];
  const float* ln2g = (const float*)d_in[18];
  const float* ln2b = (const float*)d_in[19];
  const float* lnfg = (const float*)d_in[20];
  const float* lnfb = (const float*)d_in[21];

  char* base = (char*)d_ws;
  const size_t MB = 1u << 20;
  if (ws_size < 78 * MB) return;  // defensive
  ushort* wbf = (ushort*)base;                   // 14 MB
  ushort* h   = (ushort*)(base + 14 * MB);       // 8 MB (ln out; attn Po0; attn out)
  ushort* Qb  = (ushort*)(base + 22 * MB);       // 8 MB (also MLP hidden)
  ushort* Kb  = (ushort*)(base + 30 * MB);       // 8 MB
  ushort* Ub  = (ushort*)(base + 38 * MB);       // 8 MB
  ushort* Vb  = (ushort*)(base + 46 * MB);       // 8 MB (attn Po1 after transpose)
  ushort* Vt  = (ushort*)(base + 54 * MB);       // 8 MB
  float*  xb  = (float*)(base + 62 * MB);        // 16 MB
  ushort* ab  = h;

  const size_t DD = 1048576;
  for (int i = 0; i < 2; i++){
    WP wp;
    for (int j = 0; j < 7; j++)
      wp.s[j] = (const float*)d_in[2 + 2 * j] + (size_t)i * DD;
    convert_weights<<<7 * 128, 256, 0, stream>>>(wp, wbf);
    const ushort* Wl = wbf;
    const float* xin = (i == 0) ? seqs : xb;
    ln_kernel<0><<<4096, 256, 0, stream>>>(xin, ln1g + i * D_, ln1b + i * D_, nullptr, h);
    // fused QKUV projection (N=4096) with fused RoPE on Q,K
    P4 io_qkuv = {{Qb, Kb, Ub, Vb}, {bq + i * D_, bk + i * D_, bu + i * D_, bv + i * D_}};
    gemm_k<3, 32><<<1024, 256, 0, stream>>>(h, Wl, io_qkuv, nullptr, nullptr);
    transpose_v<<<1024, 256, 0, stream>>>(Vb, Vt);
    attn_kernel<<<1024, 256, 0, stream>>>(Qb, Kb, Vt, ab, Vb);
    attn_reduce<<<4096, 256, 0, stream>>>(ab, Vb, Ub, ab);
    gemm_k2<1><<<512, 256, 0, stream>>>(ab, Wl + 4 * DD, bo + i * D_, nullptr, xin, xb);
    ln_kernel<0><<<4096, 256, 0, stream>>>(xb, ln2g + i * D_, ln2b + i * D_, nullptr, h);
    gemm_k2<2><<<512, 256, 0, stream>>>(h, Wl + 5 * DD, b1 + i * D_, Qb, nullptr, nullptr);
    gemm_k2<1><<<512, 256, 0, stream>>>(Qb, Wl + 6 * DD, b2 + i * D_, nullptr, xb, xb);
  }
  ln_kernel<1><<<4096, 256, 0, stream>>>(xb, lnfg, lnfb, (float*)d_out, nullptr);
}